// Round 5
// baseline (193.789 us; speedup 1.0000x reference)
//
#include <hip/hip_runtime.h>

#define ALPHA 0.2f
#define B_    8
#define N_    2048
#define INF_  128
#define OUTF_ 64

typedef __attribute__((ext_vector_type(8))) short short8;
typedef __attribute__((ext_vector_type(4))) float f32x4;

__device__ __forceinline__ unsigned short f2bf(float f) {
    unsigned int x = __float_as_uint(f);
    return (unsigned short)((x + 0x7fffu + ((x >> 16) & 1u)) >> 16);
}

// Kernel A: x_w = inputs @ W  -> xwT (bf16, TRANSPOSED [B][64][N]) for MFMA
// B-fragments; s1/s2 row scores (fp32). 16 rows/block, 4 rows/wave.
__global__ __launch_bounds__(256) void prep_kernel(
    const float* __restrict__ inp,    // [B*N, 128] f32
    const float* __restrict__ nodes,  // [B*N, 64]  f32
    const float* __restrict__ Wm,     // [128, 64]  f32
    const float* __restrict__ av,     // [256]      f32
    unsigned short* __restrict__ xwT, // [B][64][N] bf16
    float* __restrict__ s1_out,       // [B*N]
    float* __restrict__ s2_out)       // [B*N]
{
    __shared__ float w_lds[INF_ * OUTF_];            // 32 KB [k][f]
    __shared__ float in_lds[16 * INF_];              // 8 KB  [r][k]
    __shared__ __align__(16) unsigned short t_lds[64 * 16];  // [n][r] bf16
    const int tid  = threadIdx.x;
    const int wave = tid >> 6, lane = tid & 63;
    const int r0   = blockIdx.x * 16;

    {
        const float4* Wv = (const float4*)Wm;        // 2048 float4
        float4* wd = (float4*)w_lds;
        #pragma unroll
        for (int q = 0; q < 8; q++) wd[tid + q * 256] = Wv[tid + q * 256];
        const float4* Iv = (const float4*)(inp + (size_t)r0 * INF_);  // 512
        float4* id4 = (float4*)in_lds;
        id4[tid]       = Iv[tid];
        id4[tid + 256] = Iv[tid + 256];
    }
    __syncthreads();

    float acc[4] = {0.f, 0.f, 0.f, 0.f};
    const float* inw = &in_lds[(wave * 4) * INF_];
    #pragma unroll 4
    for (int k = 0; k < INF_; k++) {
        float wv = w_lds[k * OUTF_ + lane];     // stride-1 across lanes
        acc[0] += inw[k]            * wv;       // broadcast reads
        acc[1] += inw[INF_ + k]     * wv;
        acc[2] += inw[2 * INF_ + k] * wv;
        acc[3] += inw[3 * INF_ + k] * wv;
    }

    const float a1n = av[lane];
    const float a1x = av[64 + lane];
    const float a2n = av[128 + lane];
    const float a2x = av[192 + lane];

    #pragma unroll
    for (int rr = 0; rr < 4; rr++) {
        const int row = r0 + wave * 4 + rr;
        float nf = nodes[(size_t)row * OUTF_ + lane];
        float p1 = nf * a1n + acc[rr] * a1x;
        float p2 = nf * a2n + acc[rr] * a2x;
        #pragma unroll
        for (int off = 32; off; off >>= 1) {
            p1 += __shfl_down(p1, off);
            p2 += __shfl_down(p2, off);
        }
        if (lane == 0) { s1_out[row] = p1; s2_out[row] = p2; }
        t_lds[lane * 16 + wave * 4 + rr] = f2bf(acc[rr]);  // transpose via LDS
    }
    __syncthreads();

    {
        const int n  = tid >> 2, c0 = (tid & 3) * 4;
        const int b  = r0 >> 11, rb = r0 & (N_ - 1);
        *(uint2*)(xwT + ((size_t)b * OUTF_ + n) * N_ + rb + c0) =
            *(const uint2*)&t_lds[n * 16 + c0];
    }
}

// Kernel C: block = 16 rows of one batch; 4 waves each own a 512-col j-chunk
// of the SAME 16 rows (4 blocks/CU -> 16 waves/CU). att computed directly in
// MFMA A-frag layout, B-frags = 16B global loads from xwT (L2-resident),
// fp32 att nontemporal-stored. Partial h' reduced across waves via LDS.
__global__ __launch_bounds__(256, 4) void attn_kernel(
    const unsigned short* __restrict__ xwT,  // [B][64][N] bf16
    const float* __restrict__ s1g,           // [B*N]
    const float* __restrict__ s2g,           // [B*N]
    float* __restrict__ out_h,               // [B*N, 64] f32
    float* __restrict__ out_att)             // [B*N, N]  f32
{
    __shared__ float s2_lds[N_];             // 8 KB
    __shared__ float s1_lds[16];
    __shared__ float m_lds[16];
    __shared__ float li_lds[16];
    __shared__ float redmax[4];
    __shared__ __align__(16) float red_lds[4][16][68];  // 17.4 KB, pad 68

    const int tid  = threadIdx.x;
    const int wave = tid >> 6, lane = tid & 63;
    const int b   = blockIdx.x >> 7;          // 128 blocks per batch
    const int i0g = blockIdx.x * 16;          // global row base (flat B*N)

    {
        const float4* s2v = (const float4*)(s2g + b * N_);
        float4* d4 = (float4*)s2_lds;
        d4[tid]       = s2v[tid];
        d4[tid + 256] = s2v[tid + 256];
    }
    if (tid < 16) s1_lds[tid] = s1g[i0g + tid];
    __syncthreads();

    // batch max(s2); lrelu monotone -> m_i = lrelu(s1_i + s2max)
    {
        float lm = -1e30f;
        for (int idx = tid; idx < N_; idx += 256) lm = fmaxf(lm, s2_lds[idx]);
        #pragma unroll
        for (int off = 32; off; off >>= 1) lm = fmaxf(lm, __shfl_xor(lm, off));
        if (lane == 0) redmax[wave] = lm;
    }
    __syncthreads();
    const float s2max = fmaxf(fmaxf(redmax[0], redmax[1]),
                              fmaxf(redmax[2], redmax[3]));

    // per-row m, 1/l: 16 threads per row (128 cols each), float4 LDS reads
    {
        const int i = tid >> 4, jo = tid & 15;
        const float s1v = s1_lds[i];
        const float vm = s1v + s2max;
        const float m = vm > 0.f ? vm : ALPHA * vm;
        float l = 0.f;
        for (int j4 = jo * 4; j4 < N_; j4 += 64) {
            float4 s = *(const float4*)&s2_lds[j4];
            float v0 = s1v + s.x, v1 = s1v + s.y, v2 = s1v + s.z, v3 = s1v + s.w;
            l += __expf(fmaxf(v0, ALPHA * v0) - m);
            l += __expf(fmaxf(v1, ALPHA * v1) - m);
            l += __expf(fmaxf(v2, ALPHA * v2) - m);
            l += __expf(fmaxf(v3, ALPHA * v3) - m);
        }
        #pragma unroll
        for (int off = 8; off; off >>= 1) l += __shfl_xor(l, off);
        if (jo == 0) { m_lds[i] = m; li_lds[i] = 1.f / l; }
    }
    __syncthreads();

    const int row16 = lane & 15;             // MFMA m index (att row)
    const int quad  = lane >> 4;             // MFMA k-group
    const int jbase = wave * 512;            // this wave's j-chunk
    const float s1v = s1_lds[row16];
    const float mr  = m_lds[row16];
    const float lir = li_lds[row16];

    // B-fragment row pointers: out-col n = g*16 + row16, k offset = quad*8
    const unsigned short* bptr[4];
    #pragma unroll
    for (int g = 0; g < 4; g++)
        bptr[g] = xwT + ((size_t)b * OUTF_ + g * 16 + row16) * N_ + jbase + quad * 8;

    float* attp = out_att + (size_t)(i0g + row16) * N_ + jbase + quad * 8;
    const float* s2q = s2_lds + jbase + quad * 8;

    f32x4 acc0 = {0.f,0.f,0.f,0.f}, acc1 = {0.f,0.f,0.f,0.f};
    f32x4 acc2 = {0.f,0.f,0.f,0.f}, acc3 = {0.f,0.f,0.f,0.f};

    uint4 bnext[4];
    #pragma unroll
    for (int g = 0; g < 4; g++) bnext[g] = *(const uint4*)bptr[g];

    for (int jt = 0; jt < 512; jt += 32) {
        uint4 bc0 = bnext[0], bc1 = bnext[1], bc2 = bnext[2], bc3 = bnext[3];
        const int jn = (jt + 32) & 511;      // wrap: last prefetch harmless
        #pragma unroll
        for (int g = 0; g < 4; g++) bnext[g] = *(const uint4*)(bptr[g] + jn);

        // att values (row16, j = jbase + jt + quad*8 + jj) — A-frag layout
        float4 sa = *(const float4*)(s2q + jt);
        float4 sb = *(const float4*)(s2q + jt + 4);
        float av8[8];
        {
            float v;
            v = s1v + sa.x; av8[0] = __expf(fmaxf(v, ALPHA * v) - mr) * lir;
            v = s1v + sa.y; av8[1] = __expf(fmaxf(v, ALPHA * v) - mr) * lir;
            v = s1v + sa.z; av8[2] = __expf(fmaxf(v, ALPHA * v) - mr) * lir;
            v = s1v + sa.w; av8[3] = __expf(fmaxf(v, ALPHA * v) - mr) * lir;
            v = s1v + sb.x; av8[4] = __expf(fmaxf(v, ALPHA * v) - mr) * lir;
            v = s1v + sb.y; av8[5] = __expf(fmaxf(v, ALPHA * v) - mr) * lir;
            v = s1v + sb.z; av8[6] = __expf(fmaxf(v, ALPHA * v) - mr) * lir;
            v = s1v + sb.w; av8[7] = __expf(fmaxf(v, ALPHA * v) - mr) * lir;
        }
        // fp32 attention out, nontemporal (streaming, never re-read).
        // clang ext-vector type, NOT HIP float4 (builtin rejects class types)
        f32x4 o0 = {av8[0], av8[1], av8[2], av8[3]};
        f32x4 o1 = {av8[4], av8[5], av8[6], av8[7]};
        __builtin_nontemporal_store(o0, (f32x4*)(attp + jt));
        __builtin_nontemporal_store(o1, (f32x4*)(attp + jt + 4));

        // pack to bf16 A-frag via v_perm (truncation: err << threshold)
        uint4 pk;
        pk.x = __builtin_amdgcn_perm(__float_as_uint(av8[1]), __float_as_uint(av8[0]), 0x07060302u);
        pk.y = __builtin_amdgcn_perm(__float_as_uint(av8[3]), __float_as_uint(av8[2]), 0x07060302u);
        pk.z = __builtin_amdgcn_perm(__float_as_uint(av8[5]), __float_as_uint(av8[4]), 0x07060302u);
        pk.w = __builtin_amdgcn_perm(__float_as_uint(av8[7]), __float_as_uint(av8[6]), 0x07060302u);
        short8 a8 = *(short8*)&pk;

        acc0 = __builtin_amdgcn_mfma_f32_16x16x32_bf16(a8, *(short8*)&bc0, acc0, 0, 0, 0);
        acc1 = __builtin_amdgcn_mfma_f32_16x16x32_bf16(a8, *(short8*)&bc1, acc1, 0, 0, 0);
        acc2 = __builtin_amdgcn_mfma_f32_16x16x32_bf16(a8, *(short8*)&bc2, acc2, 0, 0, 0);
        acc3 = __builtin_amdgcn_mfma_f32_16x16x32_bf16(a8, *(short8*)&bc3, acc3, 0, 0, 0);
    }

    // write partial D tiles: D[row=quad*4+r][col=row16+16g] into red_lds[wave]
    #pragma unroll
    for (int r = 0; r < 4; r++) {
        float* rw = &red_lds[wave][quad * 4 + r][row16];
        rw[0]  = acc0[r];
        rw[16] = acc1[r];
        rw[32] = acc2[r];
        rw[48] = acc3[r];
    }
    __syncthreads();

    // cross-wave reduce + relu + store: 16 threads per row, float4 each
    {
        const int row = tid >> 4, c0 = (tid & 15) * 4;
        float4 s0 = *(const float4*)&red_lds[0][row][c0];
        float4 s1 = *(const float4*)&red_lds[1][row][c0];
        float4 s2 = *(const float4*)&red_lds[2][row][c0];
        float4 s3 = *(const float4*)&red_lds[3][row][c0];
        float4 o;
        o.x = fmaxf(s0.x + s1.x + s2.x + s3.x, 0.f);
        o.y = fmaxf(s0.y + s1.y + s2.y + s3.y, 0.f);
        o.z = fmaxf(s0.z + s1.z + s2.z + s3.z, 0.f);
        o.w = fmaxf(s0.w + s1.w + s2.w + s3.w, 0.f);
        *(float4*)(out_h + (size_t)(i0g + row) * OUTF_ + c0) = o;
    }
}

extern "C" void kernel_launch(void* const* d_in, const int* in_sizes, int n_in,
                              void* d_out, int out_size, void* d_ws, size_t ws_size,
                              hipStream_t stream) {
    const float* inp   = (const float*)d_in[0];
    const float* nodes = (const float*)d_in[1];
    const float* Wm    = (const float*)d_in[2];
    const float* av    = (const float*)d_in[3];

    float* out_h   = (float*)d_out;                                // [8,2048,64]
    float* out_att = out_h + (size_t)B_ * N_ * OUTF_;              // [8,2048,2048]

    // ws: xwT bf16 [8][64][2048] (2 MB) | s1 fp32 (64 KB) | s2 fp32 (64 KB)
    unsigned short* xwT = (unsigned short*)d_ws;
    float* s1_ws = (float*)((char*)d_ws + (size_t)B_ * OUTF_ * N_ * sizeof(unsigned short));
    float* s2_ws = s1_ws + (size_t)B_ * N_;

    prep_kernel<<<(B_ * N_) / 16, 256, 0, stream>>>(inp, nodes, Wm, av,
                                                    xwT, s1_ws, s2_ws);
    attn_kernel<<<(B_ * N_) / 16, 256, 0, stream>>>(xwT, s1_ws, s2_ws,
                                                    out_h, out_att);
}